// Round 7
// baseline (254.765 us; speedup 1.0000x reference)
//
#include <hip/hip_runtime.h>

// Conv1d as implicit GEMM on MFMA bf16 — R7.
// out[n,f,t] = sum_{c,k} x[n,c,t+k] * w[f,c,k] + b[f]
// N=32, C=64, W=4096, F=128, WW=64, out_W=4033. Output fp32.
//
// R7 vs R6: NO LDS / NO BARRIERS in the K-loop. B-frags load directly from
// the L2-resident 1MB bf16 w buffer ([c][f][k] layout, 16B/lane coalesced);
// A-frags from the bf16 x buffer (L1-hot). Explicit register double-buffer
// over channels (unroll-2 rotation) -> fine-grained vmcnt, no vmcnt(0) drain.
// R5/R6 showed the per-cg staging barrier + 2-waves/SIMD was the wall.

#define C_TOT   64
#define F_TOT   128
#define KW      64
#define OUT_W   4033
#define W_IN    4096
#define N_BATCH 32
#define T_BLK   256
#define XROW    4352          // padded bf16 x row length (shorts)

typedef __attribute__((ext_vector_type(8))) short  short8;
typedef __attribute__((ext_vector_type(4))) float  floatx4;

union Frag { unsigned int u[4]; short8 v; };

__device__ inline unsigned short f32_to_bf16(float f) {
  unsigned int u = __float_as_uint(f);
  u += 0x7FFF + ((u >> 16) & 1);
  return (unsigned short)(u >> 16);
}

// ---------------- prep: x -> bf16 rows; w -> bf16 [c][f][k] ----------------
__global__ __launch_bounds__(256) void conv1d_prep(
    const float* __restrict__ x, const float* __restrict__ w,
    unsigned short* __restrict__ xb, unsigned short* __restrict__ wcf) {
  int bid = blockIdx.x;
  if (bid < N_BATCH * C_TOT) {              // x rows: fp32 -> bf16, pad to XROW
    const float* src = x + (size_t)bid * W_IN;
    unsigned short* dst = xb + (size_t)bid * XROW;
    for (int i = threadIdx.x; i < XROW / 4; i += 256) {
      int t = i * 4;
      ushort4 o;
      if (t < W_IN) {
        float4 v = *(const float4*)(src + t);
        o.x = f32_to_bf16(v.x); o.y = f32_to_bf16(v.y);
        o.z = f32_to_bf16(v.z); o.w = f32_to_bf16(v.w);
      } else {
        o.x = o.y = o.z = o.w = 0;
      }
      *(ushort4*)(dst + t) = o;
    }
  } else {                                   // w: [f][c][k] -> bf16 [c][f][k]
    int i4 = (bid - N_BATCH * C_TOT) * 256 + threadIdx.x;  // float4 index
    if (i4 < F_TOT * C_TOT * KW / 4) {
      int k4 = (i4 & 15) * 4;
      int c  = (i4 >> 4) & 63;
      int f  = i4 >> 10;
      float4 v = *(const float4*)&w[(size_t)i4 * 4];
      ushort4 o;
      o.x = f32_to_bf16(v.x); o.y = f32_to_bf16(v.y);
      o.z = f32_to_bf16(v.z); o.w = f32_to_bf16(v.w);
      *(ushort4*)&wcf[((size_t)c * F_TOT + f) * KW + k4] = o;
    }
  }
}

// ---------------- main GEMM (barrier-free K-loop) ----------------
__global__ __launch_bounds__(256, 2) void conv1d_mfma(
    const unsigned short* __restrict__ xb, const unsigned short* __restrict__ wcf,
    const float* __restrict__ b, float* __restrict__ out) {
  __shared__ float tr[32 * 256];             // 32 KB transpose buffer (epilogue)

  const int tid  = threadIdx.x;
  const int lane = tid & 63;
  const int wv   = tid >> 6;     // 0..3
  const int q    = lane >> 4;    // 0..3
  const int col  = lane & 15;
  const int n    = blockIdx.y;
  const int t0   = blockIdx.x * T_BLK;
  const int fh2  = wv & 1;       // f half (64 f)
  const int th   = wv >> 1;      // t half (128 t)

  floatx4 acc[8][4];             // [ms][ft]
#pragma unroll
  for (int ms = 0; ms < 8; ++ms)
#pragma unroll
    for (int ft = 0; ft < 4; ++ft) acc[ms][ft] = (floatx4)0.0f;

  // A window base (shorts): 16B-aligned (all terms mult of 8)
  const unsigned short* xrowb = xb + (size_t)(n * C_TOT) * XROW + t0
                              + 8 * col + 128 * th + 8 * q;
  // B per-lane base: element (f = fh2*64 + col, k = 8q); +ft*16 f-rows, +32h k
  const unsigned short* wB = wcf + (size_t)(fh2 * 64 + col) * KW + 8 * q;

#define LOADB(B, c)                                                             \
  {                                                                             \
    const unsigned short* wp = wB + (size_t)(c) * (F_TOT * KW);                 \
    _Pragma("unroll")                                                           \
    for (int ft = 0; ft < 4; ++ft) {                                            \
      B[0][ft] = *(const short8*)(wp + ft * 16 * KW);                           \
      B[1][ft] = *(const short8*)(wp + ft * 16 * KW + 32);                      \
    }                                                                           \
  }

#define LOADA(A, c)                                                             \
  {                                                                             \
    const unsigned short* xp = xrowb + (size_t)(c) * XROW;                      \
    A[0] = *(const uint4*)(xp);      A[1] = *(const uint4*)(xp + 8);            \
    A[2] = *(const uint4*)(xp + 32); A[3] = *(const uint4*)(xp + 40);           \
  }

#define COMPUTE(Ax, Bx)                                                         \
  {                                                                             \
    _Pragma("unroll")                                                           \
    for (int h = 0; h < 2; ++h) {                                               \
      const unsigned int D[8] = {Ax[2 * h].x, Ax[2 * h].y, Ax[2 * h].z,         \
                                 Ax[2 * h].w, Ax[2 * h + 1].x, Ax[2 * h + 1].y, \
                                 Ax[2 * h + 1].z, Ax[2 * h + 1].w};             \
      Frag F8[8];                                                               \
      _Pragma("unroll")                                                         \
      for (int s = 0; s < 4; ++s)                                               \
        _Pragma("unroll")                                                       \
        for (int i = 0; i < 4; ++i) {                                           \
          F8[2 * s].u[i]     = D[s + i];                                        \
          F8[2 * s + 1].u[i] = (D[s + i] >> 16) | (D[s + i + 1] << 16);         \
        }                                                                       \
      _Pragma("unroll")                                                         \
      for (int ft = 0; ft < 4; ++ft)                                            \
        _Pragma("unroll")                                                       \
        for (int ms = 0; ms < 8; ++ms)                                          \
          acc[ms][ft] = __builtin_amdgcn_mfma_f32_16x16x32_bf16(                \
              F8[ms].v, Bx[h][ft], acc[ms][ft], 0, 0, 0);                       \
    }                                                                           \
  }

  uint4  A0[4], A1[4];
  short8 B0[2][4], B1[2][4];
  LOADA(A0, 0)
  LOADB(B0, 0)
#pragma unroll 1
  for (int c = 0; c < C_TOT; c += 2) {
    LOADA(A1, c + 1)
    LOADB(B1, c + 1)
    COMPUTE(A0, B0)
    if (c + 2 < C_TOT) { LOADA(A0, c + 2) LOADB(B0, c + 2) }
    COMPUTE(A1, B1)
  }

  // ---- epilogue: XOR-swizzled LDS transpose to [f][t], coalesced stores ----
  // acc[ms][ft][r]: t_loc = 32q + 8r + ms + 128*th, f = 64*fh2 + 16*ft + col
  const int fs_w  = fh2 * 16 + col;     // f-slot for writes (0..31)
  const int fs_r  = tid >> 3;           // f-slot for reads (0..31)
  const int seg   = tid & 7;
  const int f_r   = (fs_r >> 4) * 64 + (fs_r & 15);
  const size_t ob = ((size_t)n * F_TOT) * OUT_W;

  __syncthreads();                      // all waves done with acc compute
#pragma unroll
  for (int j = 0; j < 4; ++j) {         // round j handles ft == j (compile-time)
#pragma unroll
    for (int r = 0; r < 4; ++r)
#pragma unroll
      for (int g = 0; g < 2; ++g) {
        float4 vv;
        vv.x = acc[g * 4 + 0][j][r];
        vv.y = acc[g * 4 + 1][j][r];
        vv.z = acc[g * 4 + 2][j][r];
        vv.w = acc[g * 4 + 3][j][r];
        int chunk = 8 * q + 2 * r + g + 32 * th;       // tl>>2
        *(float4*)&tr[fs_w * 256 + ((chunk ^ (fs_w & 7)) << 2)] = vv;
      }
    __syncthreads();
    const int f = f_r + 16 * j;
    const float bias = b[f];
    const size_t obf = ob + (size_t)f * OUT_W;
#pragma unroll
    for (int j2 = 0; j2 < 8; ++j2) {
      int chunk = seg + 8 * j2;
      float4 vv = *(const float4*)&tr[fs_r * 256 + ((chunk ^ (fs_r & 7)) << 2)];
      vv.x += bias; vv.y += bias; vv.z += bias; vv.w += bias;
      int t = t0 + chunk * 4;
      if (t + 3 < OUT_W) {
        *(float4*)&out[obf + t] = vv;
      } else {
        float e[4] = {vv.x, vv.y, vv.z, vv.w};
#pragma unroll
        for (int u = 0; u < 4; ++u)
          if (t + u < OUT_W) out[obf + t + u] = e[u];
      }
    }
    __syncthreads();
  }
}

extern "C" void kernel_launch(void* const* d_in, const int* in_sizes, int n_in,
                              void* d_out, int out_size, void* d_ws, size_t ws_size,
                              hipStream_t stream) {
  const float* x = (const float*)d_in[0];
  const float* w = (const float*)d_in[1];
  const float* b = (const float*)d_in[2];
  float* out = (float*)d_out;

  unsigned short* wcf = (unsigned short*)d_ws;                      // 1 MB
  unsigned short* xb  = (unsigned short*)((char*)d_ws + (1 << 20)); // 17.8 MB

  conv1d_prep<<<N_BATCH * C_TOT + 512, 256, 0, stream>>>(x, w, xb, wcf);

  dim3 grid((OUT_W + T_BLK - 1) / T_BLK, N_BATCH);  // 16 x 32 = 512 blocks
  conv1d_mfma<<<grid, 256, 0, stream>>>(xb, wcf, b, out);
}